// Round 3
// baseline (565.812 us; speedup 1.0000x reference)
//
#include <hip/hip_runtime.h>

typedef _Float16 half8 __attribute__((ext_vector_type(8)));
typedef short short8 __attribute__((ext_vector_type(8)));
typedef float floatx4 __attribute__((ext_vector_type(4)));
typedef float float8v __attribute__((ext_vector_type(8)));

static __device__ __forceinline__ short f2bf(float f){
  union { float f; unsigned u; } v; v.f = f;
  unsigned r = v.u + 0x7fffu + ((v.u >> 16) & 1u);
  return (short)(r >> 16);
}
static __device__ __forceinline__ float bf2f(short s){
  union { unsigned u; float f; } v; v.u = ((unsigned)(unsigned short)s) << 16;
  return v.f;
}

static __device__ __forceinline__ float redmax16(float v){
  v = fmaxf(v, __shfl_xor(v, 1));
  v = fmaxf(v, __shfl_xor(v, 2));
  v = fmaxf(v, __shfl_xor(v, 4));
  v = fmaxf(v, __shfl_xor(v, 8));
  return v;
}
static __device__ __forceinline__ float redsum16(float v){
  v += __shfl_xor(v, 1);
  v += __shfl_xor(v, 2);
  v += __shfl_xor(v, 4);
  v += __shfl_xor(v, 8);
  return v;
}

// ---- fp32 [R][C] (per z-batch) -> transposed bf16 hi/lo [C][R] ----
__global__ __launch_bounds__(256) void ktransw(const float* __restrict__ src,
                                               short* __restrict__ dsth,
                                               short* __restrict__ dstl,
                                               int R, int C){
  __shared__ float tile[32][33];
  size_t boff = (size_t)blockIdx.z * R * C;
  src += boff; dsth += boff; dstl += boff;
  int r0 = blockIdx.y * 32, c0 = blockIdx.x * 32;
  int t = threadIdx.x;
  int tr = t >> 3, tc = (t & 7) * 4;
  const float* s = src + (size_t)(r0 + tr) * C + c0 + tc;
  #pragma unroll
  for (int i = 0; i < 4; i++) tile[tr][tc + i] = s[i];
  __syncthreads();
  short* dh = dsth + (size_t)(c0 + tr) * R + r0 + tc;
  short* dl = dstl + (size_t)(c0 + tr) * R + r0 + tc;
  #pragma unroll
  for (int i = 0; i < 4; i++){
    float v = tile[tc + i][tr];
    short hb = f2bf(v);
    dh[i] = hb;
    dl[i] = f2bf(v - bf2f(hb));
  }
}

// ---------------- mask -> bitmask ----------------
__global__ __launch_bounds__(256) void kmaskpack(const int* __restrict__ mask,
                                                 unsigned* __restrict__ bits){
  int w = blockIdx.x * 256 + threadIdx.x;          // 4096*128 words
  const int* p = mask + (size_t)w * 32;
  unsigned b = 0;
  #pragma unroll
  for (int i = 0; i < 32; i++) b |= (p[i] != 0) ? (1u << i) : 0u;
  bits[w] = b;
}

// ---------------- QKV projection, hi/lo 3-product for near-fp32 accuracy ----------------
// blocks x: mat(3) x head(16); y: 32 row-tiles of 128
__global__ __launch_bounds__(256,2) void kproj(
    const float* __restrict__ X, const float* __restrict__ Mm,
    const short* __restrict__ Wqth, const short* __restrict__ Wqtl,
    const short* __restrict__ Wkth, const short* __restrict__ Wktl,
    const short* __restrict__ Wvth, const short* __restrict__ Wvtl,
    _Float16* __restrict__ Qhi, _Float16* __restrict__ Qlo,
    _Float16* __restrict__ Khi, _Float16* __restrict__ Klo,
    short* __restrict__ Vt)
{
  __shared__ short Ah[128*48];
  __shared__ short Av[128*48];
  __shared__ short Bh[64*48];
  __shared__ short Bl[64*48];
  int cb = blockIdx.x, rb = blockIdx.y;
  int mat = cb >> 4, h = cb & 15;
  const float* A   = (mat == 0) ? X : Mm;
  const short* Bth = (mat == 0) ? Wqth : (mat == 1 ? Wkth : Wvth);
  const short* Btl = (mat == 0) ? Wqtl : (mat == 1 ? Wktl : Wvtl);
  Bth += (size_t)h * 64 * 1024;
  Btl += (size_t)h * 64 * 1024;
  int row0 = rb * 128;
  int t = threadIdx.x, w = t >> 6, l = t & 63, quad = l >> 4, ln = l & 15;
  floatx4 acc[2][4] = {};
  for (int d0 = 0; d0 < 1024; d0 += 32){
    #pragma unroll
    for (int i = 0; i < 2; i++){
      int u = t + i*256, r = u >> 2, s = u & 3;
      float8v v = *(const float8v*)&A[(size_t)(row0 + r)*1024 + d0 + s*8];
      short8 hh, ll;
      #pragma unroll
      for (int j = 0; j < 8; j++){
        short hb = f2bf(v[j]);
        hh[j] = hb;
        ll[j] = f2bf(v[j] - bf2f(hb));
      }
      *(short8*)&Ah[r*48 + s*8] = hh;
      *(short8*)&Av[r*48 + s*8] = ll;
    }
    { int r = t >> 2, s = t & 3;
      *(int4*)&Bh[r*48 + s*8] = *(const int4*)&Bth[(size_t)r*1024 + d0 + s*8];
      *(int4*)&Bl[r*48 + s*8] = *(const int4*)&Btl[(size_t)r*1024 + d0 + s*8]; }
    __syncthreads();
    short8 bh[4], bl[4];
    #pragma unroll
    for (int nt = 0; nt < 4; nt++){
      bh[nt] = *(short8*)&Bh[(nt*16 + ln)*48 + quad*8];
      bl[nt] = *(short8*)&Bl[(nt*16 + ln)*48 + quad*8];
    }
    #pragma unroll
    for (int mt = 0; mt < 2; mt++){
      short8 ah = *(short8*)&Ah[(w*32 + mt*16 + ln)*48 + quad*8];
      short8 al = *(short8*)&Av[(w*32 + mt*16 + ln)*48 + quad*8];
      #pragma unroll
      for (int nt = 0; nt < 4; nt++){
        acc[mt][nt] = __builtin_amdgcn_mfma_f32_16x16x32_bf16(ah, bh[nt], acc[mt][nt], 0, 0, 0);
        acc[mt][nt] = __builtin_amdgcn_mfma_f32_16x16x32_bf16(ah, bl[nt], acc[mt][nt], 0, 0, 0);
        acc[mt][nt] = __builtin_amdgcn_mfma_f32_16x16x32_bf16(al, bh[nt], acc[mt][nt], 0, 0, 0);
      }
    }
    __syncthreads();
  }
  #pragma unroll
  for (int mt = 0; mt < 2; mt++)
    #pragma unroll
    for (int nt = 0; nt < 4; nt++)
      #pragma unroll
      for (int rg = 0; rg < 4; rg++){
        int n = row0 + w*32 + mt*16 + quad*4 + rg;   // seq index
        int c = nt*16 + ln;                           // head feature
        float v = acc[mt][nt][rg];
        if (mat == 2){
          Vt[(size_t)h*64*4096 + (size_t)c*4096 + n] = f2bf(v);
        } else {
          _Float16 hi = (_Float16)v;
          _Float16 lo = (_Float16)(v - (float)hi);
          size_t idx = ((size_t)h*4096 + n)*64 + c;
          if (mat == 0){ Qhi[idx] = hi; Qlo[idx] = lo; }
          else         { Khi[idx] = hi; Klo[idx] = lo; }
        }
      }
}

// ---------------- flash attention: 16 heads x 32 q-blocks of 128 ----------------
__global__ __launch_bounds__(256,2) void kattn(
  const _Float16* __restrict__ Qhi, const _Float16* __restrict__ Qlo,
  const _Float16* __restrict__ Khi, const _Float16* __restrict__ Klo,
  const short* __restrict__ Vt, const unsigned* __restrict__ bits,
  short* __restrict__ Ows)
{
  __shared__ _Float16 Kh[64*72];
  __shared__ _Float16 Kl[64*72];
  __shared__ short    Vl[64*72];
  __shared__ short    Pl[128*72];
  __shared__ unsigned Mw[256];
  int bx = blockIdx.x, h = bx & 15, qb = bx >> 4, q0 = qb * 128;
  int t = threadIdx.x, w = t >> 6, l = t & 63, quad = l >> 4, ln = l & 15;

  half8 qh[2][2], ql[2][2];
  #pragma unroll
  for (int mt = 0; mt < 2; mt++)
    #pragma unroll
    for (int kc = 0; kc < 2; kc++){
      size_t idx = ((size_t)h*4096 + q0 + w*32 + mt*16 + ln)*64 + kc*32 + quad*8;
      qh[mt][kc] = *(const half8*)&Qhi[idx];
      ql[mt][kc] = *(const half8*)&Qlo[idx];
    }

  floatx4 o[2][4] = {};
  float mst[2][4], lst[2][4];
  #pragma unroll
  for (int mt = 0; mt < 2; mt++)
    #pragma unroll
    for (int rg = 0; rg < 4; rg++){ mst[mt][rg] = -1e30f; lst[mt][rg] = 0.f; }

  for (int kt = 0; kt < 64; kt++){
    int k0 = kt * 64;
    #pragma unroll
    for (int i = 0; i < 2; i++){
      int u = t + i*256, r = u >> 3, s = u & 7;
      size_t ksrc = ((size_t)h*4096 + k0 + r)*64 + s*8;
      *(int4*)&Kh[r*72 + s*8] = *(const int4*)&Khi[ksrc];
      *(int4*)&Kl[r*72 + s*8] = *(const int4*)&Klo[ksrc];
      *(int4*)&Vl[r*72 + s*8] = *(const int4*)&Vt[(size_t)h*64*4096 + (size_t)r*4096 + k0 + s*8];
    }
    { int r = t >> 1, u = t & 1;
      Mw[r*2 + u] = bits[(size_t)(q0 + r)*128 + (k0 >> 5) + u]; }
    __syncthreads();

    // S = Qhi*Khi + Qhi*Klo + Qlo*Khi  (near-f32 logits)
    floatx4 sa[2][4] = {};
    #pragma unroll
    for (int kc = 0; kc < 2; kc++)
      #pragma unroll
      for (int nt = 0; nt < 4; nt++){
        half8 kh = *(half8*)&Kh[(nt*16 + ln)*72 + kc*32 + quad*8];
        half8 kl = *(half8*)&Kl[(nt*16 + ln)*72 + kc*32 + quad*8];
        #pragma unroll
        for (int mt = 0; mt < 2; mt++){
          sa[mt][nt] = __builtin_amdgcn_mfma_f32_16x16x32_f16(qh[mt][kc], kh, sa[mt][nt], 0, 0, 0);
          sa[mt][nt] = __builtin_amdgcn_mfma_f32_16x16x32_f16(qh[mt][kc], kl, sa[mt][nt], 0, 0, 0);
          sa[mt][nt] = __builtin_amdgcn_mfma_f32_16x16x32_f16(ql[mt][kc], kh, sa[mt][nt], 0, 0, 0);
        }
      }

    // mask + online softmax, all-finite arithmetic
    #pragma unroll
    for (int mt = 0; mt < 2; mt++){
      #pragma unroll
      for (int nt = 0; nt < 4; nt++){
        int colb = nt*16 + ln;
        unsigned wsel = (unsigned)colb >> 5, bit = (unsigned)colb & 31;
        #pragma unroll
        for (int rg = 0; rg < 4; rg++){
          int lr = w*32 + mt*16 + quad*4 + rg;
          if (!((Mw[lr*2 + wsel] >> bit) & 1u)) sa[mt][nt][rg] = -1e30f;
        }
      }
      #pragma unroll
      for (int rg = 0; rg < 4; rg++){
        float v = fmaxf(fmaxf(sa[mt][0][rg], sa[mt][1][rg]), fmaxf(sa[mt][2][rg], sa[mt][3][rg]));
        v = redmax16(v);
        float mnew = fmaxf(mst[mt][rg], v);
        float alpha = __expf(fminf(mst[mt][rg] - mnew, 0.f));
        mst[mt][rg] = mnew;
        lst[mt][rg] *= alpha;
        #pragma unroll
        for (int vt = 0; vt < 4; vt++) o[mt][vt][rg] *= alpha;
        float sum = 0.f;
        #pragma unroll
        for (int nt = 0; nt < 4; nt++){
          float p = __expf(fminf(sa[mt][nt][rg] - mnew, 0.f));
          sa[mt][nt][rg] = p;
          sum += p;
        }
        lst[mt][rg] += redsum16(sum);
      }
      #pragma unroll
      for (int nt = 0; nt < 4; nt++)
        #pragma unroll
        for (int rg = 0; rg < 4; rg++)
          Pl[(w*32 + mt*16 + quad*4 + rg)*72 + nt*16 + ln] = f2bf(sa[mt][nt][rg]);
    }
    __syncthreads();   // P fully written before PV fragment reads

    #pragma unroll
    for (int nc = 0; nc < 2; nc++)
      #pragma unroll
      for (int mt = 0; mt < 2; mt++){
        short8 pf = *(short8*)&Pl[(w*32 + mt*16 + ln)*72 + nc*32 + quad*8];
        #pragma unroll
        for (int vt = 0; vt < 4; vt++){
          short8 vf = *(short8*)&Vl[(vt*16 + ln)*72 + nc*32 + quad*8];
          o[mt][vt] = __builtin_amdgcn_mfma_f32_16x16x32_bf16(pf, vf, o[mt][vt], 0, 0, 0);
        }
      }
    __syncthreads();
  }

  #pragma unroll
  for (int mt = 0; mt < 2; mt++)
    #pragma unroll
    for (int rg = 0; rg < 4; rg++){
      float li = lst[mt][rg];
      float inv = (li > 0.f) ? (1.f / li) : 0.f;
      int n = q0 + w*32 + mt*16 + quad*4 + rg;
      #pragma unroll
      for (int vt = 0; vt < 4; vt++){
        int col = h*64 + vt*16 + ln;
        Ows[(size_t)n*1024 + col] = f2bf(o[mt][vt][rg] * inv);
      }
    }
}

// ---------------- Y[f32] = O[4096x1024 bf16] @ Wot[1024x1024 bf16 B^T] ----------------
__global__ __launch_bounds__(256,2) void kfinal(const short* __restrict__ Ain,
                                                const short* __restrict__ Bt,
                                                float* __restrict__ Y)
{
  __shared__ short Al[128*48];
  __shared__ short Bl[64*48];
  int cb = blockIdx.x, rb = blockIdx.y;
  int row0 = rb*128, col0 = cb*64;
  int t = threadIdx.x, w = t >> 6, l = t & 63, quad = l >> 4, ln = l & 15;
  floatx4 acc[2][4] = {};
  for (int d0 = 0; d0 < 1024; d0 += 32){
    #pragma unroll
    for (int i = 0; i < 2; i++){
      int u = t + i*256, r = u >> 2, s = u & 3;
      *(int4*)&Al[r*48 + s*8] = *(const int4*)&Ain[(size_t)(row0 + r)*1024 + d0 + s*8];
    }
    { int r = t >> 2, s = t & 3;
      *(int4*)&Bl[r*48 + s*8] = *(const int4*)&Bt[(size_t)(col0 + r)*1024 + d0 + s*8]; }
    __syncthreads();
    short8 bf[4];
    #pragma unroll
    for (int nt = 0; nt < 4; nt++) bf[nt] = *(short8*)&Bl[(nt*16 + ln)*48 + quad*8];
    #pragma unroll
    for (int mt = 0; mt < 2; mt++){
      short8 af = *(short8*)&Al[(w*32 + mt*16 + ln)*48 + quad*8];
      #pragma unroll
      for (int nt = 0; nt < 4; nt++)
        acc[mt][nt] = __builtin_amdgcn_mfma_f32_16x16x32_bf16(af, bf[nt], acc[mt][nt], 0, 0, 0);
    }
    __syncthreads();
  }
  #pragma unroll
  for (int mt = 0; mt < 2; mt++)
    #pragma unroll
    for (int nt = 0; nt < 4; nt++)
      #pragma unroll
      for (int rg = 0; rg < 4; rg++){
        int n = row0 + w*32 + mt*16 + quad*4 + rg;
        int c = col0 + nt*16 + ln;
        Y[(size_t)n*1024 + c] = acc[mt][nt][rg];
      }
}

extern "C" void kernel_launch(void* const* d_in, const int* in_sizes, int n_in,
                              void* d_out, int out_size, void* d_ws, size_t ws_size,
                              hipStream_t stream){
  (void)in_sizes; (void)n_in; (void)out_size; (void)ws_size;
  const float* X    = (const float*)d_in[0];
  const float* Mm   = (const float*)d_in[1];
  const int*   mask = (const int*)d_in[2];
  const float* Wq   = (const float*)d_in[3];
  const float* Wk   = (const float*)d_in[4];
  const float* Wv   = (const float*)d_in[5];
  const float* Wo   = (const float*)d_in[6];
  float* Y = (float*)d_out;
  char* ws = (char*)d_ws;
  const size_t MB = 1024*1024;
  short*    Wqth = (short*)   (ws +  0*MB);   // [16][64][1024] bf16 hi
  short*    Wqtl = (short*)   (ws +  2*MB);
  short*    Wkth = (short*)   (ws +  4*MB);
  short*    Wktl = (short*)   (ws +  6*MB);
  short*    Wvth = (short*)   (ws +  8*MB);
  short*    Wvtl = (short*)   (ws + 10*MB);
  short*    Wot  = (short*)   (ws + 12*MB);   // [1024 d][1024 hv] bf16 hi
  short*    Wotl = (short*)   (ws + 14*MB);   // (unused lo)
  unsigned* bits = (unsigned*)(ws + 16*MB);   // [4096][128]
  _Float16* Qhi  = (_Float16*)(ws + 18*MB);   // [16][4096][64]
  _Float16* Qlo  = (_Float16*)(ws + 26*MB);
  _Float16* Khi  = (_Float16*)(ws + 34*MB);
  _Float16* Klo  = (_Float16*)(ws + 42*MB);
  short*    Vt   = (short*)   (ws + 50*MB);   // [16][64][4096]
  short*    Ows  = (short*)   (ws + 58*MB);   // [4096][1024]

  ktransw<<<dim3(2,32,16), 256, 0, stream>>>(Wq, Wqth, Wqtl, 1024, 64);
  ktransw<<<dim3(2,32,16), 256, 0, stream>>>(Wk, Wkth, Wktl, 1024, 64);
  ktransw<<<dim3(2,32,16), 256, 0, stream>>>(Wv, Wvth, Wvtl, 1024, 64);
  ktransw<<<dim3(32,32,1), 256, 0, stream>>>(Wo, Wot, Wotl, 1024, 1024);
  kmaskpack<<<2048, 256, 0, stream>>>(mask, bits);
  kproj<<<dim3(48,32), 256, 0, stream>>>(X, Mm, Wqth, Wqtl, Wkth, Wktl, Wvth, Wvtl,
                                         Qhi, Qlo, Khi, Klo, Vt);
  kattn<<<512, 256, 0, stream>>>(Qhi, Qlo, Khi, Klo, Vt, bits, Ows);
  kfinal<<<dim3(16,32), 256, 0, stream>>>(Ows, Wot, Y);
}